// Round 1
// baseline (438.663 us; speedup 1.0000x reference)
//
#include <hip/hip_runtime.h>
#include <math.h>

// Problem constants (B=16, T=3000, F=201)
constexpr int BB     = 16;
constexpr int T      = 3000;
constexpr int F      = 201;
constexpr int NFFT   = 400;            // 2*(F-1)
constexpr int HOP    = 160;
constexpr int K      = 402;            // 2*F (real/imag interleaved)
constexpr int KP     = 416;            // K padded to multiple of 16
constexpr int M      = BB * T;         // 48000 rows
constexpr int ESTLEN = (T - 1) * HOP + NFFT;   // 480240
constexpr int OUTLEN = ESTLEN - NFFT;          // 479840 per batch
constexpr float EPS  = 1e-12f;

// ---------------- table builders ----------------

// W[k][j], k in [0,KP), j in [0,400). Rows >= 402 are zero.
__global__ void build_w(float* __restrict__ Wt) {
    int idx = blockIdx.x * blockDim.x + threadIdx.x;
    if (idx >= KP * NFFT) return;
    int k = idx / NFFT;
    int j = idx - k * NFFT;
    float v = 0.f;
    if (k < K) {
        int f = k >> 1;
        bool is_re = (k & 1) == 0;
        float c = (f == 0 || f == F - 1) ? (1.f / 400.f) : (2.f / 400.f);
        int m = (j * f) % NFFT;                       // exact angle reduction
        float ang = (float)(2.0 * M_PI * (double)m / 400.0);
        float tw = is_re ? cosf(ang) : -sinf(ang);
        float win = 0.54f - 0.46f * cosf((float)(2.0 * M_PI * (double)j / 400.0));
        v = c * tw * win;
    }
    Wt[idx] = v;
}

__global__ void build_ssw(float* __restrict__ ssw) {
    int p = blockIdx.x * blockDim.x + threadIdx.x;
    if (p >= ESTLEN) return;
    int t_hi = p / HOP; if (t_hi > T - 1) t_hi = T - 1;
    int t_lo = (p >= NFFT) ? ((p - NFFT) / HOP + 1) : 0;
    float s = 0.f;
    for (int t = t_lo; t <= t_hi; ++t) {
        int j = p - t * HOP;
        float w = 0.54f - 0.46f * cosf((float)(2.0 * M_PI * (double)j / 400.0));
        s += w * w;
    }
    ssw[p] = s;
}

// ---------------- GEMM + overlap-add (atomic) ----------------
// A: [M][K] fp32 (input, contiguous). Wt: [KP][400]. out: [BB][OUTLEN], pre-zeroed.
#define BM 64
#define BN 64
#define BK 16

__global__ __launch_bounds__(256)
void gemm_oa(const float* __restrict__ A, const float* __restrict__ Wt,
             float* __restrict__ out) {
    __shared__ float As[BK][BM + 4];   // [k][r], padded
    __shared__ float Bs[BK][BN];       // [k][j]

    const int tid = threadIdx.x;
    const int r0 = blockIdx.y * BM;
    const int j0 = blockIdx.x * BN;
    const int tx = tid & 15;           // 0..15 -> j micro
    const int ty = tid >> 4;           // 0..15 -> r micro

    float acc[4][4] = {};

    // load mapping
    const int a_k = tid & 15;          // 0..15
    const int a_r = (tid >> 4) * 4;    // 0,4,...,60
    const int b_j = tid & 63;          // 0..63
    const int b_k = (tid >> 6) * 4;    // 0,4,8,12
    const bool bj_ok = (j0 + b_j) < NFFT;

    for (int k0 = 0; k0 < KP; k0 += BK) {
        // A tile 64x16 -> As[k][r]
        #pragma unroll
        for (int i = 0; i < 4; ++i) {
            int r = r0 + a_r + i;
            int k = k0 + a_k;
            As[a_k][a_r + i] = (k < K) ? A[(size_t)r * K + k] : 0.f;
        }
        // B tile 16x64 -> Bs[k][j] (Wt rows 402..415 are zero-filled)
        #pragma unroll
        for (int i = 0; i < 4; ++i) {
            int k = k0 + b_k + i;
            Bs[b_k + i][b_j] = bj_ok ? Wt[k * NFFT + j0 + b_j] : 0.f;
        }
        __syncthreads();

        #pragma unroll
        for (int kk = 0; kk < BK; ++kk) {
            float4 a4 = *reinterpret_cast<const float4*>(&As[kk][ty * 4]);
            float4 b4 = *reinterpret_cast<const float4*>(&Bs[kk][tx * 4]);
            const float a[4] = {a4.x, a4.y, a4.z, a4.w};
            const float b[4] = {b4.x, b4.y, b4.z, b4.w};
            #pragma unroll
            for (int i = 0; i < 4; ++i)
                #pragma unroll
                for (int j = 0; j < 4; ++j)
                    acc[i][j] = fmaf(a[i], b[j], acc[i][j]);
        }
        __syncthreads();
    }

    // epilogue: scatter each q[r][j] into out[b][160*t + j - 200]
    #pragma unroll
    for (int i = 0; i < 4; ++i) {
        int r = r0 + ty * 4 + i;
        int bb = r / T;
        int tt = r - bb * T;
        #pragma unroll
        for (int jj = 0; jj < 4; ++jj) {
            int j = j0 + tx * 4 + jj;
            if (j < NFFT) {
                int pos = tt * HOP + j - (NFFT / 2);
                if (pos >= 0 && pos < OUTLEN) {
                    atomicAdd(&out[(size_t)bb * OUTLEN + pos], acc[i][jj]);
                }
            }
        }
    }
}

// ---------------- normalize ----------------
__global__ void normalize_k(float* __restrict__ out, const float* __restrict__ ssw) {
    int idx = blockIdx.x * blockDim.x + threadIdx.x;
    if (idx >= BB * OUTLEN) return;
    int p = idx % OUTLEN;
    float s = ssw[p + NFFT / 2];
    float v = out[idx];
    out[idx] = (s > EPS) ? v / s : v;
}

// ---------------- launcher ----------------
extern "C" void kernel_launch(void* const* d_in, const int* in_sizes, int n_in,
                              void* d_out, int out_size, void* d_ws, size_t ws_size,
                              hipStream_t stream) {
    const float* x = (const float*)d_in[0];
    float* out = (float*)d_out;

    float* Wt  = (float*)d_ws;                       // KP*400 floats
    float* ssw = (float*)d_ws + (size_t)KP * NFFT;   // ESTLEN floats

    // zero output (harness poisons it; we accumulate atomically)
    hipMemsetAsync(d_out, 0, (size_t)out_size * sizeof(float), stream);

    {
        int total = KP * NFFT;
        build_w<<<(total + 255) / 256, 256, 0, stream>>>(Wt);
    }
    {
        build_ssw<<<(ESTLEN + 255) / 256, 256, 0, stream>>>(ssw);
    }
    {
        dim3 grid((NFFT + BN - 1) / BN, M / BM);     // (7, 750)
        gemm_oa<<<grid, 256, 0, stream>>>(x, Wt, out);
    }
    {
        int total = BB * OUTLEN;
        normalize_k<<<(total + 255) / 256, 256, 0, stream>>>(out, ssw);
    }
}

// Round 2
// 66.615 us; speedup vs baseline: 6.5851x; 6.5851x over previous
//
#include <hip/hip_runtime.h>
#include <math.h>

// Problem constants (B=16, T=3000, F=201)
constexpr int BB     = 16;
constexpr int T      = 3000;
constexpr int F      = 201;
constexpr int NFFT   = 400;            // 2*(F-1)
constexpr int HOP    = 160;
constexpr int K      = 402;            // 2*F (real/imag interleaved)
constexpr int KP     = 416;            // K padded to multiple of 32
constexpr int JP     = 480;            // padded W cols: m + 160*dt, dt=0..2
constexpr int ESTLEN = (T - 1) * HOP + NFFT;   // 480240
constexpr int OUTLEN = ESTLEN - NFFT;          // 479840 per batch
constexpr float EPS  = 1e-12f;

typedef short bf16x8 __attribute__((ext_vector_type(8)));
typedef float f32x4  __attribute__((ext_vector_type(4)));

__device__ __forceinline__ unsigned short f2bf(float f) {
    unsigned int u = __float_as_uint(f);
    u = (u + 0x7fffu + ((u >> 16) & 1u)) >> 16;
    return (unsigned short)u;
}

// ---------------- table builders ----------------

// Wt2[j][k] bf16, j in [0,480), k in [0,416). Transposed + padded weight table.
// W[k][j] = c_f * (re? cos : -sin)(2*pi*j*f/400) * win[j]
__global__ void build_wt2(unsigned short* __restrict__ Wt2) {
    int idx = blockIdx.x * blockDim.x + threadIdx.x;
    if (idx >= JP * KP) return;
    int j = idx / KP;
    int k = idx - j * KP;
    float v = 0.f;
    if (j < NFFT && k < K) {
        int f = k >> 1;
        bool is_re = (k & 1) == 0;
        float c = (f == 0 || f == F - 1) ? (1.f / 400.f) : (2.f / 400.f);
        int m = (j * f) % NFFT;                       // exact angle reduction
        float ang = (float)(2.0 * M_PI * (double)m / 400.0);
        float tw = is_re ? cosf(ang) : -sinf(ang);
        float win = 0.54f - 0.46f * cosf((float)(2.0 * M_PI * (double)j / 400.0));
        v = c * tw * win;
    }
    Wt2[idx] = f2bf(v);
}

__global__ void build_ssw(float* __restrict__ ssw) {
    int p = blockIdx.x * blockDim.x + threadIdx.x;
    if (p >= ESTLEN) return;
    int t_hi = p / HOP; if (t_hi > T - 1) t_hi = T - 1;
    int t_lo = (p >= NFFT) ? ((p - NFFT) / HOP + 1) : 0;
    float s = 0.f;
    for (int t = t_lo; t <= t_hi; ++t) {
        int j = p - t * HOP;
        float w = 0.54f - 0.46f * cosf((float)(2.0 * M_PI * (double)j / 400.0));
        s += w * w;
    }
    ssw[p] = s;
}

// ---------------- fused MFMA gather-GEMM ----------------
// Block: 64 u-rows x 160 m-cols of output. 4 waves, each wave 16u x 160m.
// K loop: 13 steps of 32, 3 taps per step.
// LDS: As[66][40] bf16 (A rows u0-2..u0+63, +8 pad stride), Ws[480][32] bf16
// (chunk-XOR-swizzled, filled by global_load_lds from pre-swizzled source).

__global__ __launch_bounds__(256)
void istft_fused(const float* __restrict__ A, const unsigned short* __restrict__ Wt2,
                 const float* __restrict__ ssw, float* __restrict__ out) {
    __shared__ unsigned short As[66 * 40];
    __shared__ unsigned short Ws[JP * 32];

    const int tid  = threadIdx.x;
    const int lane = tid & 63;
    const int w    = tid >> 6;          // wave id 0..3
    const int bx   = blockIdx.x;        // u-chunk
    const int b    = blockIdx.y;        // batch
    const int u0   = 1 + bx * 64;

    const int lrow = lane & 15;
    const int lkg  = lane >> 4;         // k-group 0..3

    f32x4 acc[10];
    #pragma unroll
    for (int mt = 0; mt < 10; ++mt) acc[mt] = (f32x4){0.f, 0.f, 0.f, 0.f};

    // A staging map: 256 threads cover rows 0..63 (4 k-quads each); rows 64,65 by tid<8
    const int ar  = tid >> 2;           // 0..63
    const int akq = (tid & 3) * 8;      // 0,8,16,24

    for (int ks = 0; ks < 13; ++ks) {
        const int k0 = ks * 32;

        // ---- stage A (fp32 -> bf16, reg-staged) ----
        {
            #pragma unroll
            for (int pass = 0; pass < 2; ++pass) {
                int r  = (pass == 0) ? ar : (64 + (tid >> 2));
                bool active = (pass == 0) || (tid < 8);
                if (active) {
                    int t = u0 - 2 + r;
                    unsigned short vs[8];
                    if (t >= 0 && t < T) {
                        const float* src = A + ((size_t)(b * T + t)) * K + k0 + akq;
                        #pragma unroll
                        for (int i = 0; i < 4; ++i) {
                            int kk = k0 + akq + 2 * i;
                            float2 fv = make_float2(0.f, 0.f);
                            if (kk < K) fv = *reinterpret_cast<const float2*>(src + 2 * i);
                            vs[2 * i]     = f2bf(fv.x);
                            vs[2 * i + 1] = f2bf(fv.y);
                        }
                    } else {
                        #pragma unroll
                        for (int i = 0; i < 8; ++i) vs[i] = 0;
                    }
                    *reinterpret_cast<bf16x8*>(&As[r * 40 + akq]) =
                        *reinterpret_cast<const bf16x8*>(vs);
                }
            }
        }

        // ---- stage W via global_load_lds (16B chunks, source pre-swizzled) ----
        // physical chunk P = j*4 + c'; holds logical chunk c = c' ^ ((j>>1)&3)
        {
            #pragma unroll
            for (int it = 0; it < 8; ++it) {
                int P = it * 256 + tid;
                if (P < JP * 4) {                       // wave-uniform branch
                    int j  = P >> 2;
                    int cp = P & 3;
                    int c  = cp ^ ((j >> 1) & 3);
                    const unsigned short* g = Wt2 + (size_t)j * KP + k0 + c * 8;
                    unsigned short* l = &Ws[(size_t)(it * 256 + w * 64) * 8];
                    __builtin_amdgcn_global_load_lds(
                        (const __attribute__((address_space(1))) void*)g,
                        (__attribute__((address_space(3))) void*)l,
                        16, 0, 0);
                }
            }
        }

        __syncthreads();

        // ---- compute: 3 taps x 10 m-tiles ----
        bf16x8 afrag[3];
        #pragma unroll
        for (int dt = 0; dt < 3; ++dt) {
            int rs = w * 16 + lrow + 2 - dt;
            afrag[dt] = *reinterpret_cast<const bf16x8*>(&As[rs * 40 + lkg * 8]);
        }
        #pragma unroll
        for (int mt = 0; mt < 10; ++mt) {
            #pragma unroll
            for (int dt = 0; dt < 3; ++dt) {
                int j    = dt * 160 + mt * 16 + lrow;
                int phys = (j << 2) | (lkg ^ ((j >> 1) & 3));
                bf16x8 bfrag = *reinterpret_cast<const bf16x8*>(&Ws[phys * 8]);
                acc[mt] = __builtin_amdgcn_mfma_f32_16x16x32_bf16(
                    afrag[dt], bfrag, acc[mt], 0, 0, 0);
            }
        }

        __syncthreads();
    }

    // ---- epilogue: normalized plain stores (each output owned by one block) ----
    #pragma unroll
    for (int mt = 0; mt < 10; ++mt) {
        int m = mt * 16 + lrow;
        #pragma unroll
        for (int q = 0; q < 4; ++q) {
            int u  = u0 + w * 16 + lkg * 4 + q;
            int pe = 160 * u + m;
            int po = pe - (NFFT / 2);
            if (po >= 0 && po < OUTLEN) {
                float s = ssw[pe];
                float v = acc[mt][q];
                out[(size_t)b * OUTLEN + po] = (s > EPS) ? v / s : v;
            }
        }
    }
}

// ---------------- launcher ----------------
extern "C" void kernel_launch(void* const* d_in, const int* in_sizes, int n_in,
                              void* d_out, int out_size, void* d_ws, size_t ws_size,
                              hipStream_t stream) {
    const float* x = (const float*)d_in[0];
    float* out = (float*)d_out;

    unsigned short* Wt2 = (unsigned short*)d_ws;               // JP*KP ushort = 399,360 B
    float* ssw = (float*)((char*)d_ws + 400000);               // ESTLEN floats

    {
        int total = JP * KP;
        build_wt2<<<(total + 255) / 256, 256, 0, stream>>>(Wt2);
    }
    {
        build_ssw<<<(ESTLEN + 255) / 256, 256, 0, stream>>>(ssw);
    }
    {
        dim3 grid(47, BB);                                     // 47*64 >= 3000 u-values
        istft_fused<<<grid, 256, 0, stream>>>(x, Wt2, ssw, out);
    }
}